// Round 6
// baseline (1898.201 us; speedup 1.0000x reference)
//
#include <hip/hip_runtime.h>

__global__ void k_fill(unsigned* p, int n, unsigned v) {
    int i = blockIdx.x * blockDim.x + threadIdx.x;
    if (i < n) p[i] = v;
}

// ---------------- CSR build (graph identical across layers; built once) ----------------
__global__ void k_hist(const int* __restrict__ ei, int E, int* __restrict__ deg) {
    int e = blockIdx.x * blockDim.x + threadIdx.x;
    if (e < E) atomicAdd(&deg[ei[E + e]], 1);
}

__global__ void k_scan_blocks(const int* __restrict__ deg, int N,
                              int* __restrict__ excl, int* __restrict__ parts) {
    __shared__ int s[256];
    int t = threadIdx.x, i = blockIdx.x * 256 + t;
    int v = (i < N) ? deg[i] : 0;
    s[t] = v;
    __syncthreads();
    int acc = v;
    for (int off = 1; off < 256; off <<= 1) {
        int add = (t >= off) ? s[t - off] : 0;
        __syncthreads();
        acc += add;
        s[t] = acc;
        __syncthreads();
    }
    if (i < N) excl[i] = acc - v;
    if (t == 255) parts[blockIdx.x] = acc;
}

__global__ void k_scan_parts(int* __restrict__ parts, int nb) {
    __shared__ int s[256];
    int t = threadIdx.x;
    int v = (t < nb) ? parts[t] : 0;
    s[t] = v;
    __syncthreads();
    int acc = v;
    for (int off = 1; off < 256; off <<= 1) {
        int add = (t >= off) ? s[t - off] : 0;
        __syncthreads();
        acc += add;
        s[t] = acc;
        __syncthreads();
    }
    if (t < nb) parts[t] = acc - v;
}

__global__ void k_scan_add(const int* __restrict__ excl, const int* __restrict__ parts,
                           int* __restrict__ row_ptr, int* __restrict__ cursor, int N) {
    int i = blockIdx.x * blockDim.x + threadIdx.x;
    if (i >= N) return;
    int r = excl[i] + parts[i >> 8];
    row_ptr[i] = r;
    cursor[i] = r;
}

__global__ void k_scatter(const int* __restrict__ ei, int E, int* __restrict__ cursor,
                          int2* __restrict__ elist) {
    int e = blockIdx.x * blockDim.x + threadIdx.x;
    if (e >= E) return;
    int d = ei[E + e];
    int j = atomicAdd(&cursor[d], 1);
    elist[j] = make_int2(ei[e], e);
}

// permute edge_attr into CSR order: ea_s[j] = ea[elist[j].y]  (8 threads per edge)
__global__ void k_reorder(const int2* __restrict__ elist, const float* __restrict__ ea, int E,
                          float4* __restrict__ ea_s) {
    int idx = blockIdx.x * blockDim.x + threadIdx.x;
    int j = idx >> 3, q = idx & 7;
    if (j >= E) return;
    ea_s[(size_t)j * 8 + q] = ((const float4*)ea)[(size_t)elist[j].y * 8 + q];
}

// ---------------- Dual GEMM: out{l,r} = A @ W{l,r} + b{l,r} ----------------
template <int M, int RW>
__global__ __launch_bounds__(256) void k_gemm2(const float* __restrict__ A,
                                               const float* __restrict__ Wl, const float* __restrict__ bl,
                                               const float* __restrict__ Wr, const float* __restrict__ br,
                                               float* __restrict__ outl, float* __restrict__ outr) {
    constexpr int TX = M / 4;
    __shared__ float sA[32][68];
    __shared__ float sW[32][M];
    const float* W    = blockIdx.y ? Wr : Wl;
    const float* bias = blockIdx.y ? br : bl;
    float* out        = blockIdx.y ? outr : outl;
    int t = threadIdx.x;
    int tx = t % TX, ty = t / TX;
    int r0 = blockIdx.x * 64;
    float acc[RW][4] = {};
    for (int kt = 0; kt < 128; kt += 32) {
        for (int l = t; l < 512; l += 256) {
            int row = l >> 3, kq = (l & 7) << 2;
            float4 a = *(const float4*)&A[(size_t)(r0 + row) * 128 + kt + kq];
            sA[kq + 0][row] = a.x; sA[kq + 1][row] = a.y;
            sA[kq + 2][row] = a.z; sA[kq + 3][row] = a.w;
        }
        for (int l = t; l < 32 * M / 4; l += 256) {
            int kk = (l * 4) / M, cc = (l * 4) % M;
            *(float4*)&sW[kk][cc] = *(const float4*)&W[(size_t)(kt + kk) * M + cc];
        }
        __syncthreads();
#pragma unroll
        for (int k = 0; k < 32; k++) {
            float4 w = *(float4*)&sW[k][tx * 4];
            float ar[RW];
#pragma unroll
            for (int i = 0; i < RW; i += 4) {
                float4 a = *(float4*)&sA[k][ty * RW + i];
                ar[i] = a.x; ar[i + 1] = a.y; ar[i + 2] = a.z; ar[i + 3] = a.w;
            }
#pragma unroll
            for (int i = 0; i < RW; i++) {
                acc[i][0] += ar[i] * w.x; acc[i][1] += ar[i] * w.y;
                acc[i][2] += ar[i] * w.z; acc[i][3] += ar[i] * w.w;
            }
        }
        __syncthreads();
    }
    float4 b = *(const float4*)&bias[tx * 4];
#pragma unroll
    for (int i = 0; i < RW; i++) {
        float4 v;
        v.x = acc[i][0] + b.x; v.y = acc[i][1] + b.y;
        v.z = acc[i][2] + b.z; v.w = acc[i][3] + b.w;
        *(float4*)&out[(size_t)(r0 + ty * RW + i) * M + tx * 4] = v;
    }
}

// ---------------- Fused per-dst GATv2 aggregation (CSR, zero atomics) ----------------
// HC=128 (H=2): one wave per (node, head) -> halves the per-edge serial chain, 2x waves.
// HC=64  (H=1): one wave per node.
// Edge loop unrolled x2: two independent gather+reduce chains overlap.
// SORTED: edge features pre-permuted to CSR order (sequential reads).
template <int HC, bool RELU, bool SORTED>
__global__ __launch_bounds__(256) void k_agg(const float* __restrict__ xl, const float* __restrict__ xr,
                                             const float* __restrict__ ea, const float4* __restrict__ ea_s,
                                             const int2* __restrict__ elist,
                                             const int* __restrict__ row_ptr, const int* __restrict__ deg,
                                             const float* __restrict__ We, const float* __restrict__ att,
                                             const float* __restrict__ bias, float* __restrict__ out, int N) {
    int tid = threadIdx.x, wv = tid >> 6, lane = tid & 63;
    int n, col;
    if constexpr (HC == 128) {
        n = blockIdx.x * 2 + (wv >> 1);
        col = ((wv & 1) << 6) | lane;
    } else {
        n = blockIdx.x * 4 + wv;
        col = lane;
    }
    float rWe[32];
#pragma unroll
    for (int k = 0; k < 32; k++) rWe[k] = We[k * HC + col];
    float attc = att[col], bc = bias[col];
    if (n >= N) return;
    int start = row_ptr[n], d = deg[n];
    float xrc = xr[(size_t)n * HC + col];
    float acc = 0.f, den = 0.f;
    int j = 0;
    for (; j + 2 <= d; j += 2) {
        int2 spA = elist[start + j];
        int2 spB = elist[start + j + 1];
        const float4* eapA = SORTED ? (ea_s + (size_t)(start + j) * 8)
                                    : (const float4*)(ea + (size_t)spA.y * 32);
        const float4* eapB = SORTED ? (ea_s + (size_t)(start + j + 1) * 8)
                                    : (const float4*)(ea + (size_t)spB.y * 32);
        float xlA = xl[(size_t)spA.x * HC + col];
        float xlB = xl[(size_t)spB.x * HC + col];
        float eeA = 0.f, eeB = 0.f;
#pragma unroll
        for (int kq = 0; kq < 8; kq++) {
            float4 va = eapA[kq];
            float4 vb = eapB[kq];
            eeA = fmaf(va.x, rWe[kq * 4 + 0], eeA);
            eeA = fmaf(va.y, rWe[kq * 4 + 1], eeA);
            eeA = fmaf(va.z, rWe[kq * 4 + 2], eeA);
            eeA = fmaf(va.w, rWe[kq * 4 + 3], eeA);
            eeB = fmaf(vb.x, rWe[kq * 4 + 0], eeB);
            eeB = fmaf(vb.y, rWe[kq * 4 + 1], eeB);
            eeB = fmaf(vb.z, rWe[kq * 4 + 2], eeB);
            eeB = fmaf(vb.w, rWe[kq * 4 + 3], eeB);
        }
        float vA = xlA + xrc + eeA;
        vA = vA > 0.f ? vA : 0.2f * vA;
        float vB = xlB + xrc + eeB;
        vB = vB > 0.f ? vB : 0.2f * vB;
        float pA = attc * vA, pB = attc * vB;
#pragma unroll
        for (int m = 32; m; m >>= 1) {
            pA += __shfl_xor(pA, m);
            pB += __shfl_xor(pB, m);
        }
        float exA = __expf(pA), exB = __expf(pB);
        acc = fmaf(exA, xlA, acc); den += exA;
        acc = fmaf(exB, xlB, acc); den += exB;
    }
    if (j < d) {
        int2 sp = elist[start + j];
        const float4* eap = SORTED ? (ea_s + (size_t)(start + j) * 8)
                                   : (const float4*)(ea + (size_t)sp.y * 32);
        float xlA = xl[(size_t)sp.x * HC + col];
        float ee = 0.f;
#pragma unroll
        for (int kq = 0; kq < 8; kq++) {
            float4 v = eap[kq];
            ee = fmaf(v.x, rWe[kq * 4 + 0], ee);
            ee = fmaf(v.y, rWe[kq * 4 + 1], ee);
            ee = fmaf(v.z, rWe[kq * 4 + 2], ee);
            ee = fmaf(v.w, rWe[kq * 4 + 3], ee);
        }
        float v = xlA + xrc + ee;
        v = v > 0.f ? v : 0.2f * v;
        float p = attc * v;
#pragma unroll
        for (int m = 32; m; m >>= 1) p += __shfl_xor(p, m);
        float ex = __expf(p);
        acc = fmaf(ex, xlA, acc); den += ex;
    }
    float o = acc / (den + 1e-16f) + bc;
    if (RELU) o = o > 0.f ? o : 0.f;
    out[(size_t)n * HC + col] = o;
}

// ---------------- gate MLP: gate[n] = exp(relu(h[n]@G1w+G1b)@G2w + G2b) ----------------
__global__ __launch_bounds__(256) void k_gate(const float* __restrict__ h, const float* __restrict__ G1w,
                                              const float* __restrict__ G1b, const float* __restrict__ G2w,
                                              const float* __restrict__ G2b,
                                              float* __restrict__ gate, int N) {
    __shared__ float sH[64][64];
    __shared__ float part[64][2];
    int t = threadIdx.x;
    int n0 = blockIdx.x * 64;
    for (int l = t; l < 1024; l += 256) {
        float4 v = ((const float4*)(h + (size_t)n0 * 64))[l];
        int n = l >> 4, kq = (l & 15) << 2;
        *(float4*)&sH[n][kq] = v;
    }
    int c = t & 127, half = t >> 7;
    float rW[64];
#pragma unroll
    for (int k = 0; k < 64; k++) rW[k] = G1w[k * 128 + c];
    float g1b = G1b[c], g2w = G2w[c];
    __syncthreads();
    for (int nn = 0; nn < 32; nn++) {
        int n = half * 32 + nn;
        float acc = g1b;
#pragma unroll
        for (int k = 0; k < 64; k += 4) {
            float4 hv = *(const float4*)&sH[n][k];
            acc = fmaf(hv.x, rW[k], acc);
            acc = fmaf(hv.y, rW[k + 1], acc);
            acc = fmaf(hv.z, rW[k + 2], acc);
            acc = fmaf(hv.w, rW[k + 3], acc);
        }
        acc = acc > 0.f ? acc : 0.f;
        float p = acc * g2w;
#pragma unroll
        for (int m = 32; m; m >>= 1) p += __shfl_xor(p, m);
        if ((t & 63) == 0) part[n][(t >> 6) & 1] = p;
    }
    __syncthreads();
    if (t < 64) gate[n0 + t] = __expf(part[t][0] + part[t][1] + G2b[0]);
}

// ---------------- pooling: one block per graph (batch sorted -> binary search range) ----------------
__global__ __launch_bounds__(256) void k_pool(const float* __restrict__ h, const float* __restrict__ gate,
                                              const int* __restrict__ batch,
                                              float* __restrict__ pooled, int N) {
    int g = blockIdx.x;
    int lo = 0, hi = N;
    while (lo < hi) { int mid = (lo + hi) >> 1; if (batch[mid] < g) lo = mid + 1; else hi = mid; }
    int start = lo;
    lo = 0; hi = N;
    while (lo < hi) { int mid = (lo + hi) >> 1; if (batch[mid] < g + 1) lo = mid + 1; else hi = mid; }
    int end = lo;
    int t = threadIdx.x, wv = t >> 6, lane = t & 63;
    float acc = 0.f, den = 0.f;
    for (int n = start + wv; n < end; n += 4) {
        float gv = gate[n];
        acc = fmaf(gv, h[(size_t)n * 64 + lane], acc);
        den += gv;
    }
    __shared__ float sacc[4][64];
    __shared__ float sden[4];
    sacc[wv][lane] = acc;
    if (lane == 0) sden[wv] = den;
    __syncthreads();
    if (wv == 0) {
        float a = sacc[0][lane] + sacc[1][lane] + sacc[2][lane] + sacc[3][lane];
        float d = sden[0] + sden[1] + sden[2] + sden[3] + 1e-16f;
        pooled[g * 64 + lane] = a / d;
    }
}

__global__ void k_final(const float* __restrict__ pooled, const float* __restrict__ Wreg,
                        const float* __restrict__ breg, float* __restrict__ out) {
    int g = threadIdx.x;
    float acc = breg[0];
    for (int c = 0; c < 64; c++) acc += pooled[g * 64 + c] * Wreg[c];
    out[g] = acc;
}

extern "C" void kernel_launch(void* const* d_in, const int* in_sizes, int n_in,
                              void* d_out, int out_size, void* d_ws, size_t ws_size,
                              hipStream_t stream) {
    const float* x  = (const float*)d_in[0];
    const float* ea = (const float*)d_in[1];
    const int* ei    = (const int*)d_in[2];
    const int* batch = (const int*)d_in[3];
    auto ff = [&](int i) { return (const float*)d_in[i]; };
    const float *W1l = ff(4), *b1l = ff(5), *W1r = ff(6), *b1r = ff(7), *W1e = ff(8),
                *att1 = ff(9), *bias1 = ff(10);
    const float *W2l = ff(11), *b2l = ff(12), *W2r = ff(13), *b2r = ff(14), *W2e = ff(15),
                *att2 = ff(16), *bias2 = ff(17);
    const float *W3l = ff(18), *b3l = ff(19), *W3r = ff(20), *b3r = ff(21), *W3e = ff(22),
                *att3 = ff(23), *bias3 = ff(24);
    const float *G1w = ff(25), *G1b = ff(26), *G2w = ff(27), *G2b = ff(28), *Wreg = ff(29),
                *breg = ff(30);

    const int N = in_sizes[0] / 128;  // 40000
    const int E = in_sizes[2] / 2;    // 640000

    char* ws = (char*)d_ws;
    float*  bufA    = (float*)(ws);              // [N,128]
    float*  bufB    = (float*)(ws + 20480000);   // [N,128]
    float*  bufH    = (float*)(ws + 40960000);   // [N,128]
    int2*   elist   = (int2*)(ws + 61440000);    // [E] (src, edge_id)
    int*    row_ptr = (int*)(ws + 66560000);     // [N]
    int*    deg     = (int*)(ws + 66720000);     // [N]
    int*    cursor  = (int*)(ws + 66880000);     // [N]
    int*    excl    = (int*)(ws + 67040000);     // [N]
    int*    parts   = (int*)(ws + 67200000);     // [<=256]
    float*  gate    = (float*)(ws + 67204096);   // [N]
    float*  pooled  = (float*)(ws + 67364096);   // [64,64]
    float4* ea_s    = (float4*)(ws + 67380480);  // [E,32] floats, CSR-ordered (optional)
    const bool sorted_ea = ws_size >= (size_t)67380480 + (size_t)E * 32 * 4;

    auto cdiv = [](int a, int b) { return (a + b - 1) / b; };
    const int NB = cdiv(N, 256);
    const dim3 gemmG(N / 64, 2);

    // ---- CSR build (once; graph shared by all 3 layers) ----
    k_fill<<<NB, 256, 0, stream>>>((unsigned*)deg, N, 0u);
    k_hist<<<cdiv(E, 256), 256, 0, stream>>>(ei, E, deg);
    k_scan_blocks<<<NB, 256, 0, stream>>>(deg, N, excl, parts);
    k_scan_parts<<<1, 256, 0, stream>>>(parts, NB);
    k_scan_add<<<NB, 256, 0, stream>>>(excl, parts, row_ptr, cursor, N);
    k_scatter<<<cdiv(E, 256), 256, 0, stream>>>(ei, E, cursor, elist);
    if (sorted_ea)
        k_reorder<<<cdiv(E * 8, 256), 256, 0, stream>>>(elist, ea, E, ea_s);

    // ---- layer 1 ----
    k_gemm2<128, 8><<<gemmG, 256, 0, stream>>>(x, W1l, b1l, W1r, b1r, bufA, bufB);
    if (sorted_ea)
        k_agg<128, true, true><<<cdiv(N, 2), 256, 0, stream>>>(bufA, bufB, ea, ea_s, elist, row_ptr, deg, W1e, att1, bias1, bufH, N);
    else
        k_agg<128, true, false><<<cdiv(N, 2), 256, 0, stream>>>(bufA, bufB, ea, ea_s, elist, row_ptr, deg, W1e, att1, bias1, bufH, N);

    // ---- layer 2 ----
    k_gemm2<128, 8><<<gemmG, 256, 0, stream>>>(bufH, W2l, b2l, W2r, b2r, bufA, bufB);
    if (sorted_ea)
        k_agg<128, true, true><<<cdiv(N, 2), 256, 0, stream>>>(bufA, bufB, ea, ea_s, elist, row_ptr, deg, W2e, att2, bias2, bufH, N);
    else
        k_agg<128, true, false><<<cdiv(N, 2), 256, 0, stream>>>(bufA, bufB, ea, ea_s, elist, row_ptr, deg, W2e, att2, bias2, bufH, N);

    // ---- layer 3 ----
    k_gemm2<64, 4><<<gemmG, 256, 0, stream>>>(bufH, W3l, b3l, W3r, b3r, bufA, bufB);
    if (sorted_ea)
        k_agg<64, false, true><<<cdiv(N, 4), 256, 0, stream>>>(bufA, bufB, ea, ea_s, elist, row_ptr, deg, W3e, att3, bias3, bufH, N);
    else
        k_agg<64, false, false><<<cdiv(N, 4), 256, 0, stream>>>(bufA, bufB, ea, ea_s, elist, row_ptr, deg, W3e, att3, bias3, bufH, N);

    // ---- attentional pooling + regressor ----
    k_gate<<<N / 64, 256, 0, stream>>>(bufH, G1w, G1b, G2w, G2b, gate, N);
    k_pool<<<64, 256, 0, stream>>>(bufH, gate, batch, pooled, N);
    k_final<<<1, 64, 0, stream>>>(pooled, Wreg, breg, (float*)d_out);
}